// Round 8
// baseline (137.912 us; speedup 1.0000x reference)
//
#include <hip/hip_runtime.h>
#include <hip/hip_bf16.h>
#include <hip/hip_fp16.h>

// ARAPLoss: out[b] = mean_e | ||x[b,dst]-x[b,src]||^2 - ||dx[b,dst]-dx[b,src]||^2 |
// B=8, NV=100000, E ~ 1.19M directed dedup edges (sorted by src, symmetric).
//
// R1: batch-inner, unpacked -> L2 thrash, 345us main.
// R2: f32 pack + batch-per-XCD -> 66us main. Fixed harness overhead ~73us.
// R3: unpacked -> 97us. R4: single-atomic compaction -> 220us prep (cross-XCD
//     same-line atomics: NEVER funnel many waves through one line).
// R5: f16 recs + s<d predication -> 64us. R6: int4 idx + 4 edges/iter -> 58us.
// KEY: R2/R5/R6 all ~60us despite 4x gather-work and 4x iteration deltas.
//     Invariant: every XCD walks the FULL edge list for its batch (9.5M
//     edge-computations, ~9.5M random-line touches, 76MB index stream).
// R8: process each undirected edge ONCE for ALL 8 batches. Record = 8 batches
//     x 6 f16 = 96B (2 lines). Random line touches 8x down, indices 8x down,
//     edge-computations 8x down. Per-block partials via PLAIN STORES to ws +
//     tiny reducer kernel (no atomics, no d_out memset).

#define NBATCH 8
#define NVERT 100000
#define MAIN_BLOCKS 4096
#define HPV 48  // halves per vertex record (8 batches * 6)

// ---- prep: rec[v] = concat_b {x0,x1,x2,dx0,dx1,dx2}_f16  (96B, 16B-aligned) ----
__global__ __launch_bounds__(256) void arap_pack96_kernel(
    const float* __restrict__ dx, const float* __restrict__ x,
    __half* __restrict__ recs)
{
    const int v = blockIdx.x * blockDim.x + threadIdx.x;
    if (v >= NVERT) return;
    __half tmp[HPV];
#pragma unroll
    for (int b = 0; b < NBATCH; ++b) {
        const size_t s = (size_t)b * NVERT * 3 + (size_t)v * 3;
        tmp[b * 6 + 0] = __float2half_rn(x[s]);
        tmp[b * 6 + 1] = __float2half_rn(x[s + 1]);
        tmp[b * 6 + 2] = __float2half_rn(x[s + 2]);
        tmp[b * 6 + 3] = __float2half_rn(dx[s]);
        tmp[b * 6 + 4] = __float2half_rn(dx[s + 1]);
        tmp[b * 6 + 5] = __float2half_rn(dx[s + 2]);
    }
    float4* __restrict__ dstp = (float4*)(recs + (size_t)v * HPV);
    const float4* srcp = (const float4*)tmp;
#pragma unroll
    for (int i = 0; i < 6; ++i) dstp[i] = srcp[i];
}

// ---- main: one thread per directed edge, active iff src<dst; all 8 batches ----
__global__ __launch_bounds__(256) void arap_main96_kernel(
    const __half* __restrict__ recs,
    const int* __restrict__ src, const int* __restrict__ dst,
    float* __restrict__ partial, int E)
{
    float acc[NBATCH];
#pragma unroll
    for (int b = 0; b < NBATCH; ++b) acc[b] = 0.0f;

    const int tid = blockIdx.x * blockDim.x + threadIdx.x;
    const int stride = gridDim.x * blockDim.x;

    for (int e = tid; e < E; e += stride) {
        const int s = __builtin_nontemporal_load(src + e);
        const int d = __builtin_nontemporal_load(dst + e);
        if (s < d) {  // symmetric edge set: count each undirected edge once (x2 in scale)
            const float4* __restrict__ rs = (const float4*)(recs + (size_t)s * HPV);
            const float4* __restrict__ rd = (const float4*)(recs + (size_t)d * HPV);
            // two groups of 4 batches; 6 independent 16B gathers per group
#pragma unroll
            for (int g = 0; g < 2; ++g) {
                float4 a0 = rs[g * 3], a1 = rs[g * 3 + 1], a2 = rs[g * 3 + 2];
                float4 c0 = rd[g * 3], c1 = rd[g * 3 + 1], c2 = rd[g * 3 + 2];
                const __half* ah = (const __half*)&a0;  // a0,a1,a2 contiguous? no —
                // use per-float4 half views (each float4 = 8 halves = 2 batches' worth * ... )
                // layout: group g covers batches 4g..4g+3, halves [24g .. 24g+23]
                const __half* av[3] = {(const __half*)&a0, (const __half*)&a1, (const __half*)&a2};
                const __half* cv[3] = {(const __half*)&c0, (const __half*)&c1, (const __half*)&c2};
#pragma unroll
                for (int j = 0; j < 4; ++j) {           // batch within group
                    const int h0 = j * 6;               // half index within 24-half group
                    float t[6];
#pragma unroll
                    for (int k = 0; k < 6; ++k) {
                        const int hi = h0 + k;
                        t[k] = __half2float(cv[hi >> 3][hi & 7]) - __half2float(av[hi >> 3][hi & 7]);
                    }
                    const float diffx  = t[0] * t[0] + t[1] * t[1] + t[2] * t[2];
                    const float diffdx = t[3] * t[3] + t[4] * t[4] + t[5] * t[5];
                    acc[4 * g + j] += fabsf(diffx - diffdx);
                }
                (void)ah;
            }
        }
    }

    // 64-lane wave reduction for each of the 8 accumulators
#pragma unroll
    for (int b = 0; b < NBATCH; ++b) {
#pragma unroll
        for (int off = 32; off > 0; off >>= 1)
            acc[b] += __shfl_down(acc[b], off, 64);
    }

    __shared__ float red[4][NBATCH];
    const int wave = threadIdx.x >> 6;
    const int lane = threadIdx.x & 63;
    if (lane == 0) {
#pragma unroll
        for (int b = 0; b < NBATCH; ++b) red[wave][b] = acc[b];
    }
    __syncthreads();
    if (threadIdx.x < NBATCH) {  // plain stores — no atomics (R4 lesson)
        const int b = threadIdx.x;
        partial[(size_t)blockIdx.x * NBATCH + b] =
            red[0][b] + red[1][b] + red[2][b] + red[3][b];
    }
}

// ---- reducer: 1 block; sum MAIN_BLOCKS x 8 partials, scale, write out ----
__global__ __launch_bounds__(256) void arap_reduce_kernel(
    const float* __restrict__ partial, float* __restrict__ out, float scale)
{
    const int t = threadIdx.x;
    const int b = t >> 5;          // 8 batches x 32 threads
    const int k = t & 31;
    float v = 0.0f;
    for (int i = k; i < MAIN_BLOCKS; i += 32)
        v += partial[(size_t)i * NBATCH + b];
#pragma unroll
    for (int off = 16; off > 0; off >>= 1)
        v += __shfl_down(v, off, 32);
    if (k == 0) out[b] = v * scale;
}

// ---- fallback (tiny ws): R1 kernel, self-contained ----
__global__ __launch_bounds__(256) void arap_edge_kernel(
    const float* __restrict__ dx, const float* __restrict__ x,
    const int* __restrict__ src, const int* __restrict__ dst,
    float* __restrict__ out, int E, float invE)
{
    float acc[NBATCH];
#pragma unroll
    for (int b = 0; b < NBATCH; ++b) acc[b] = 0.0f;
    const int stride = gridDim.x * blockDim.x;
    const size_t bstride = (size_t)NVERT * 3;
    for (int e = blockIdx.x * blockDim.x + threadIdx.x; e < E; e += stride) {
        const int s = src[e] * 3;
        const int d = dst[e] * 3;
#pragma unroll
        for (int b = 0; b < NBATCH; ++b) {
            const float* __restrict__ xb  = x  + b * bstride;
            const float* __restrict__ dxb = dx + b * bstride;
            float ex0 = xb[d] - xb[s], ex1 = xb[d+1] - xb[s+1], ex2 = xb[d+2] - xb[s+2];
            float ed0 = dxb[d] - dxb[s], ed1 = dxb[d+1] - dxb[s+1], ed2 = dxb[d+2] - dxb[s+2];
            acc[b] += fabsf(ex0*ex0 + ex1*ex1 + ex2*ex2 - (ed0*ed0 + ed1*ed1 + ed2*ed2));
        }
    }
#pragma unroll
    for (int b = 0; b < NBATCH; ++b)
#pragma unroll
        for (int off = 32; off > 0; off >>= 1)
            acc[b] += __shfl_down(acc[b], off, 64);
    __shared__ float red[4][NBATCH];
    const int wave = threadIdx.x >> 6;
    const int lane = threadIdx.x & 63;
    if (lane == 0)
#pragma unroll
        for (int b = 0; b < NBATCH; ++b) red[wave][b] = acc[b];
    __syncthreads();
    if (threadIdx.x == 0)
#pragma unroll
        for (int b = 0; b < NBATCH; ++b)
            atomicAdd(&out[b], (red[0][b] + red[1][b] + red[2][b] + red[3][b]) * invE);
}

extern "C" void kernel_launch(void* const* d_in, const int* in_sizes, int n_in,
                              void* d_out, int out_size, void* d_ws, size_t ws_size,
                              hipStream_t stream) {
    const float* dx = (const float*)d_in[0];
    const float* x  = (const float*)d_in[1];
    const int* edge_src = (const int*)d_in[2];
    const int* edge_dst = (const int*)d_in[3];
    float* out = (float*)d_out;

    const int E = in_sizes[2];
    const float scale2 = 2.0f / (float)E;

    const size_t rec_bytes = (size_t)NVERT * HPV * sizeof(__half);       // 9.6 MB
    const size_t part_off  = (rec_bytes + 255) & ~(size_t)255;
    const size_t need = part_off + (size_t)MAIN_BLOCKS * NBATCH * sizeof(float);

    if (ws_size >= need) {
        __half* recs = (__half*)d_ws;
        float* partial = (float*)((char*)d_ws + part_off);

        arap_pack96_kernel<<<(NVERT + 255) / 256, 256, 0, stream>>>(dx, x, recs);
        arap_main96_kernel<<<MAIN_BLOCKS, 256, 0, stream>>>(recs, edge_src, edge_dst,
                                                            partial, E);
        arap_reduce_kernel<<<1, 256, 0, stream>>>(partial, out, scale2);
    } else {
        (void)hipMemsetAsync(d_out, 0, NBATCH * sizeof(float), stream);
        int blocks = (E + 255) / 256;
        if (blocks > 2048) blocks = 2048;
        arap_edge_kernel<<<blocks, 256, 0, stream>>>(dx, x, edge_src, edge_dst,
                                                     out, E, 1.0f / (float)E);
    }
}